// Round 11
// baseline (276.226 us; speedup 1.0000x reference)
//
#include <hip/hip_runtime.h>
#include <hip/hip_bf16.h>

typedef short short8 __attribute__((ext_vector_type(8)));
typedef float floatx4 __attribute__((ext_vector_type(4)));

#define B_   8
#define N_   2048
#define FIN_ 64
#define H_   4
#define D_   32
#define HD_  128
#define JH_  1024
#define ALPHA_ 0.2f
#define LOG2E_ 1.4426950408889634f

// ws layout (bytes):
//   WhT  bf16 [B][H][32][N]       @ 0      (4 MB)   d-major, MFMA B-frags
//   src  fp32 [B][H][N] (x log2e) @ 4 MB   (256 KB)
//   dstb bf16 [B][H][N] (x log2e) @ 4.25MB (128 KB)
//   pO   fp32 [2][B][N][HD]       @ 8 MB   (16 MB)  per-j-half partial PV
//   pW   fp32 [2][B][H][N]        @ 24 MB  (512 KB) per-j-half partial wsum

__device__ __forceinline__ float fexp2(float x) {
#if __has_builtin(__builtin_amdgcn_exp2f)
    return __builtin_amdgcn_exp2f(x);
#else
    float r; asm("v_exp_f32 %0, %1" : "=v"(r) : "v"(x)); return r;
#endif
}

__device__ __forceinline__ unsigned pk2bf(float x, float y) {   // RNE pack (prep only)
    unsigned ux = __builtin_bit_cast(unsigned, x);
    ux = (ux + 0x7fffu + ((ux >> 16) & 1u)) >> 16;
    unsigned uy = __builtin_bit_cast(unsigned, y);
    uy = (uy + 0x7fffu + ((uy >> 16) & 1u)) >> 16;
    return ux | (uy << 16);
}

// truncating pack of two fp32 high halves -> one instr (v_perm_b32)
__device__ __forceinline__ unsigned pktrunc(float x, float y) {
    unsigned ux = __builtin_bit_cast(unsigned, x);
    unsigned uy = __builtin_bit_cast(unsigned, y);
#if __has_builtin(__builtin_amdgcn_perm)
    return __builtin_amdgcn_perm(uy, ux, 0x07060302u);  // {hi16(y), hi16(x)}
#else
    return (ux >> 16) | (uy & 0xffff0000u);
#endif
}

// ---------------- prep: Wh = h@W; WhT bf16 (d-major), src/dst (x log2e) ------
__global__ __launch_bounds__(256) void gat_prep2(
    const float* __restrict__ h, const float* __restrict__ W, const float* __restrict__ a,
    unsigned short* __restrict__ WhT, float* __restrict__ src, unsigned short* __restrict__ dstb)
{
    __shared__ float Ws[FIN_][HD_];
    __shared__ float hsT[FIN_][36];
    int bx = blockIdx.x;
    int b = bx >> 6;
    int n0 = (bx & 63) * 32;
    int tid = threadIdx.x;

    #pragma unroll
    for (int it = 0; it < 8; ++it) {
        int idx = it * 256 + tid;
        int k = idx >> 5, c4 = (idx & 31) << 2;
        *(float4*)&Ws[k][c4] = *(const float4*)&W[k * HD_ + c4];
    }
    #pragma unroll
    for (int it = 0; it < 8; ++it) {
        int idx = it * 256 + tid;
        int r = idx >> 6, k = idx & 63;
        hsT[k][r] = h[((size_t)b * N_ + n0 + r) * FIN_ + k];
    }
    __syncthreads();

    int c = tid & 127;
    int rq = tid >> 7;
    float acc[16];
    #pragma unroll
    for (int r = 0; r < 16; ++r) acc[r] = 0.f;
    for (int k = 0; k < FIN_; ++k) {
        float wv = Ws[k][c];
        float4 h0 = *(const float4*)&hsT[k][rq * 16];
        float4 h1 = *(const float4*)&hsT[k][rq * 16 + 4];
        float4 h2 = *(const float4*)&hsT[k][rq * 16 + 8];
        float4 h3 = *(const float4*)&hsT[k][rq * 16 + 12];
        acc[0]  += h0.x * wv; acc[1]  += h0.y * wv; acc[2]  += h0.z * wv; acc[3]  += h0.w * wv;
        acc[4]  += h1.x * wv; acc[5]  += h1.y * wv; acc[6]  += h1.z * wv; acc[7]  += h1.w * wv;
        acc[8]  += h2.x * wv; acc[9]  += h2.y * wv; acc[10] += h2.z * wv; acc[11] += h2.w * wv;
        acc[12] += h3.x * wv; acc[13] += h3.y * wv; acc[14] += h3.z * wv; acc[15] += h3.w * wv;
    }

    __attribute__((aligned(16))) unsigned pk[8];
    #pragma unroll
    for (int q = 0; q < 8; ++q) pk[q] = pk2bf(acc[2 * q], acc[2 * q + 1]);
    unsigned short* wrow = WhT + ((size_t)b * HD_ + c) * N_ + n0 + rq * 16;
    *(uint4*)wrow       = *(uint4*)&pk[0];
    *(uint4*)(wrow + 8) = *(uint4*)&pk[4];

    int hh = c >> 5, d = c & 31;
    float a1v = a[hh * 64 + d];
    float a2v = a[hh * 64 + 32 + d];
    #pragma unroll
    for (int r = 0; r < 16; ++r) {
        float s1 = acc[r] * a1v;
        float s2 = acc[r] * a2v;
        #pragma unroll
        for (int off = 16; off >= 1; off >>= 1) {
            s1 += __shfl_xor(s1, off, 32);
            s2 += __shfl_xor(s2, off, 32);
        }
        if (d == 0) {
            int n = n0 + rq * 16 + r;
            src[(b * H_ + hh) * N_ + n] = s1 * LOG2E_;
            unsigned u = __builtin_bit_cast(unsigned, s2 * LOG2E_);
            u = (u + 0x7fffu + ((u >> 16) & 1u)) >> 16;
            dstb[(b * H_ + hh) * N_ + n] = (unsigned short)u;
        }
    }
}

// ------ main: j-split x2 (8 blocks/CU), ballot adj, prefetch, MFMA PV --------
__global__ __launch_bounds__(256, 8) void gat_main8(
    const int* __restrict__ adj, const unsigned short* __restrict__ WhT,
    const float* __restrict__ src, const unsigned short* __restrict__ dstb,
    float* __restrict__ pO, float* __restrict__ pW)
{
    __shared__ unsigned short dsts[H_ * JH_];  // 8 KB (this j-half)
    __shared__ unsigned adjW[16][36];          // 32 words + pad

    int bx = blockIdx.x;
    int b    = bx >> 8;
    int rest = bx & 255;
    int half = rest & 1;
    int i0   = (rest >> 1) * 16;
    int jb   = half * JH_;
    int tid = threadIdx.x;
    int wv = tid >> 6, l = tid & 63;

    #pragma unroll
    for (int it = 0; it < 2; ++it) {           // dst half: 4096 ushorts = 512 uint4
        int idx = it * 256 + tid;
        int hh = idx >> 7, off = (idx & 127) * 8;
        *(uint4*)&dsts[hh * JH_ + off] =
            *(const uint4*)&dstb[(size_t)(b * H_ + hh) * N_ + jb + off];
    }

    // adj staging: wave wv owns rows wv*4..+3 of this j-half; ballot packs 64->u64
    const int* adjBase = adj + ((size_t)(b * N_ + i0 + wv * 4)) * N_ + jb + l;

    int vals[16];                              // in-flight group: 4 rows x 4 chunks
    #pragma unroll
    for (int rr = 0; rr < 4; ++rr)
        #pragma unroll
        for (int cc = 0; cc < 4; ++cc)
            vals[rr * 4 + cc] = adjBase[rr * N_ + cc * 64];

    int h = wv, g = l >> 4, m = l & 15;
    int g8 = g << 3;
    float src_r = src[(b * H_ + h) * N_ + i0 + m];
    const unsigned short* WhR0 = WhT + ((size_t)(b * H_ + h) * 32 + m) * N_ + jb;
    const unsigned short* WhR1 = WhR0 + (size_t)16 * N_;
    const unsigned short* dstH = &dsts[h * JH_];

    short8 ones;
    #pragma unroll
    for (int q = 0; q < 8; ++q) ones[q] = (short)0x3F80;   // bf16 1.0

    floatx4 acc0 = {0.f, 0.f, 0.f, 0.f};
    floatx4 acc1 = {0.f, 0.f, 0.f, 0.f};
    floatx4 acc2 = {0.f, 0.f, 0.f, 0.f};

    short8 bf0_c = *(const short8*)&WhR0[g8];
    short8 bf1_c = *(const short8*)&WhR1[g8];
    uint4 dv_c;                                // valid after first barrier

    for (int q = 0; q < 4; ++q) {
        // ---- ballot group q into LDS (loads already in flight)
        #pragma unroll
        for (int rr = 0; rr < 4; ++rr)
            #pragma unroll
            for (int cc = 0; cc < 4; ++cc) {
                unsigned long long mk = __ballot(vals[rr * 4 + cc] != 0);
                if (l == 0) {
                    int c = q * 4 + cc;
                    adjW[wv * 4 + rr][2 * c]     = (unsigned)mk;
                    adjW[wv * 4 + rr][2 * c + 1] = (unsigned)(mk >> 32);
                }
            }
        __syncthreads();                        // staging q visible (disjoint words/group)
        if (q == 0) dv_c = *(const uint4*)&dstH[g8];

        // ---- issue group q+1 adj loads (hidden behind compute below)
        if (q < 3) {
            #pragma unroll
            for (int rr = 0; rr < 4; ++rr)
                #pragma unroll
                for (int cc = 0; cc < 4; ++cc)
                    vals[rr * 4 + cc] = adjBase[rr * N_ + (q + 1) * 256 + cc * 64];
        }

        // ---- compute 8 MFMA K-chunks of group q (j in [q*256, q*256+256))
        for (int jj = 0; jj < 8; ++jj) {
            int it = q * 8 + jj;
            int j0n = ((it + 1) << 5) + g8;     // next chunk (it=31: harmless overread)
            short8 bf0_n = *(const short8*)&WhR0[j0n];
            short8 bf1_n = *(const short8*)&WhR1[j0n];
            uint4  dv_n  = *(const uint4*)&dstH[(j0n < JH_) ? j0n : g8];

            unsigned sh = adjW[m][it] >> g8;    // broadcast read, this lane's 8 bits
            const unsigned* du = (const unsigned*)&dv_c;
            unsigned pk[4];
            #pragma unroll
            for (int c2 = 0; c2 < 4; ++c2) {
                float dlo = __builtin_bit_cast(float, du[c2] << 16);
                float dhi = __builtin_bit_cast(float, du[c2] & 0xffff0000u);
                float e0 = src_r + dlo;
                float e1 = src_r + dhi;
                e0 = fmaxf(e0, ALPHA_ * e0);    // lrelu (log2e>0 commutes)
                e1 = fmaxf(e1, ALPHA_ * e1);
                float m0 = (float)((sh >> (2 * c2)) & 1u);      // vcc-free mask
                float m1 = (float)((sh >> (2 * c2 + 1)) & 1u);
                float x0 = fexp2(e0) * m0;
                float x1 = fexp2(e1) * m1;
                pk[c2] = pktrunc(x0, x1);       // 1-op truncating bf16 pack
            }
            short8 af = __builtin_bit_cast(short8, *(uint4*)pk);
            acc0 = __builtin_amdgcn_mfma_f32_16x16x32_bf16(af, bf0_c, acc0, 0, 0, 0);
            acc1 = __builtin_amdgcn_mfma_f32_16x16x32_bf16(af, bf1_c, acc1, 0, 0, 0);
            acc2 = __builtin_amdgcn_mfma_f32_16x16x32_bf16(af, ones,  acc2, 0, 0, 0);
            bf0_c = bf0_n; bf1_c = bf1_n; dv_c = dv_n;
        }
    }

    // partial row-sums + partial PV (C/D: col=m, row=g*4+r)
    if (m == 0) {
        #pragma unroll
        for (int r = 0; r < 4; ++r)
            pW[(((size_t)half * B_ + b) * H_ + h) * N_ + i0 + g * 4 + r] = acc2[r];
    }
    #pragma unroll
    for (int r = 0; r < 4; ++r) {
        size_t o = ((size_t)(half * B_ + b) * N_ + i0 + g * 4 + r) * HD_ + h * 32 + m;
        pO[o]      = acc0[r];
        pO[o + 16] = acc1[r];
    }
}

// ---------------- finalize: sum halves, divide by wsum, write out ------------
__global__ __launch_bounds__(256) void gat_fin(
    const float* __restrict__ pO, const float* __restrict__ pW, float* __restrict__ out)
{
    int gid = blockIdx.x * 256 + threadIdx.x;    // float4 index, 524288 total
    int c4 = (gid & 31) << 2;
    int i  = (gid >> 5) & (N_ - 1);
    int b  = gid >> 16;
    int hh = c4 >> 5;
    float w0 = pW[((size_t)b * H_ + hh) * N_ + i];
    float w1 = pW[(((size_t)B_ + b) * H_ + hh) * N_ + i];
    float inv = 1.f / (w0 + w1);
    size_t o = ((size_t)b * N_ + i) * HD_ + c4;
    float4 v0 = *(const float4*)&pO[o];
    float4 v1 = *(const float4*)&pO[(size_t)B_ * N_ * HD_ + o];
    float4 r;
    r.x = (v0.x + v1.x) * inv;
    r.y = (v0.y + v1.y) * inv;
    r.z = (v0.z + v1.z) * inv;
    r.w = (v0.w + v1.w) * inv;
    *(float4*)&out[o] = r;
}

extern "C" void kernel_launch(void* const* d_in, const int* in_sizes, int n_in,
                              void* d_out, int out_size, void* d_ws, size_t ws_size,
                              hipStream_t stream) {
    const float* h   = (const float*)d_in[0];
    const int*   adj = (const int*)d_in[1];
    const float* W   = (const float*)d_in[2];
    const float* a   = (const float*)d_in[3];
    float* out = (float*)d_out;

    unsigned short* WhT  = (unsigned short*)d_ws;
    float*          src  = (float*)((char*)d_ws + 4u * 1024 * 1024);
    unsigned short* dstb = (unsigned short*)((char*)d_ws + 4u * 1024 * 1024 + 256u * 1024);
    float*          pO   = (float*)((char*)d_ws + 8u * 1024 * 1024);
    float*          pW   = (float*)((char*)d_ws + 24u * 1024 * 1024);

    gat_prep2<<<B_ * (N_ / 32), 256, 0, stream>>>(h, W, a, WhT, src, dstb);
    gat_main8<<<B_ * (N_ / 16) * 2, 256, 0, stream>>>(adj, WhT, src, dstb, pO, pW);
    gat_fin<<<(B_ * N_ * HD_ / 4) / 256, 256, 0, stream>>>(pO, pW, out);
}

// Round 12
// 239.828 us; speedup vs baseline: 1.1518x; 1.1518x over previous
//
#include <hip/hip_runtime.h>
#include <hip/hip_bf16.h>

typedef short short8 __attribute__((ext_vector_type(8)));
typedef float floatx4 __attribute__((ext_vector_type(4)));

#define B_   8
#define N_   2048
#define FIN_ 64
#define H_   4
#define D_   32
#define HD_  128
#define ALPHA_ 0.2f
#define LOG2E_ 1.4426950408889634f

// ws layout (bytes):
//   WhF  bf16 [B][H][64 chunk][2 half][64 lane][8]  @ 0      (4 MB)
//        = MFMA B-fragments pre-arranged lane-contiguous (coalesced loads)
//   src  fp32 [B][H][N] (x log2e)                   @ 4 MB   (256 KB)
//   dstb bf16 [B][H][N] (x log2e)                   @ 4.25MB (128 KB)

__device__ __forceinline__ float fexp2(float x) {
#if __has_builtin(__builtin_amdgcn_exp2f)
    return __builtin_amdgcn_exp2f(x);
#else
    float r; asm("v_exp_f32 %0, %1" : "=v"(r) : "v"(x)); return r;
#endif
}

__device__ __forceinline__ unsigned pk2bf(float x, float y) {   // RNE pack (prep only)
    unsigned ux = __builtin_bit_cast(unsigned, x);
    ux = (ux + 0x7fffu + ((ux >> 16) & 1u)) >> 16;
    unsigned uy = __builtin_bit_cast(unsigned, y);
    uy = (uy + 0x7fffu + ((uy >> 16) & 1u)) >> 16;
    return ux | (uy << 16);
}

// truncating pack of two fp32 high halves -> one instr (v_perm_b32)
__device__ __forceinline__ unsigned pktrunc(float x, float y) {
    unsigned ux = __builtin_bit_cast(unsigned, x);
    unsigned uy = __builtin_bit_cast(unsigned, y);
#if __has_builtin(__builtin_amdgcn_perm)
    return __builtin_amdgcn_perm(uy, ux, 0x07060302u);  // {hi16(y), hi16(x)}
#else
    return (ux >> 16) | (uy & 0xffff0000u);
#endif
}

// ---- prep: Wh = h@W; WhF fragment-layout bf16, src/dst (x log2e) ------------
__global__ __launch_bounds__(256) void gat_prep3(
    const float* __restrict__ h, const float* __restrict__ W, const float* __restrict__ a,
    unsigned short* __restrict__ WhF, float* __restrict__ src, unsigned short* __restrict__ dstb)
{
    __shared__ float Ws[FIN_][HD_];
    __shared__ float hsT[FIN_][36];
    int bx = blockIdx.x;
    int b = bx >> 6;
    int n0 = (bx & 63) * 32;            // 32 graph nodes (j) per block
    int tid = threadIdx.x;

    #pragma unroll
    for (int it = 0; it < 8; ++it) {
        int idx = it * 256 + tid;
        int k = idx >> 5, c4 = (idx & 31) << 2;
        *(float4*)&Ws[k][c4] = *(const float4*)&W[k * HD_ + c4];
    }
    #pragma unroll
    for (int it = 0; it < 8; ++it) {
        int idx = it * 256 + tid;
        int r = idx >> 6, k = idx & 63;
        hsT[k][r] = h[((size_t)b * N_ + n0 + r) * FIN_ + k];
    }
    __syncthreads();

    int c = tid & 127;                  // output column = h*32+d
    int rq = tid >> 7;                  // 16-row half
    int hh = c >> 5, d = c & 31;
    float acc[16];
    #pragma unroll
    for (int r = 0; r < 16; ++r) acc[r] = 0.f;
    for (int k = 0; k < FIN_; ++k) {
        float wv = Ws[k][c];
        float4 h0 = *(const float4*)&hsT[k][rq * 16];
        float4 h1 = *(const float4*)&hsT[k][rq * 16 + 4];
        float4 h2 = *(const float4*)&hsT[k][rq * 16 + 8];
        float4 h3 = *(const float4*)&hsT[k][rq * 16 + 12];
        acc[0]  += h0.x * wv; acc[1]  += h0.y * wv; acc[2]  += h0.z * wv; acc[3]  += h0.w * wv;
        acc[4]  += h1.x * wv; acc[5]  += h1.y * wv; acc[6]  += h1.z * wv; acc[7]  += h1.w * wv;
        acc[8]  += h2.x * wv; acc[9]  += h2.y * wv; acc[10] += h2.z * wv; acc[11] += h2.w * wv;
        acc[12] += h3.x * wv; acc[13] += h3.y * wv; acc[14] += h3.z * wv; acc[15] += h3.w * wv;
    }

    // FragB write: Wh[j = n0+rq*16+r][col c] -> WhF[b][hh][it][half][g*16+n][e]
    //   it = j>>5, g = (j>>3)&3, e = j&7, half = d>>4, n = d&15
    {
        int half = d >> 4, n = d & 15;
        int j0 = n0 + rq * 16;
        int it0 = j0 >> 5;
        int g0 = (j0 >> 3) & 3;         // 0 or 2; spans g0, g0+1
        #pragma unroll
        for (int rr = 0; rr < 2; ++rr) {
            __attribute__((aligned(16))) unsigned pk4[4];
            #pragma unroll
            for (int q = 0; q < 4; ++q)
                pk4[q] = pk2bf(acc[rr * 8 + 2 * q], acc[rr * 8 + 2 * q + 1]);
            size_t fi = ((((size_t)b * H_ + hh) * 64 + it0) * 2 + half) * 64
                        + (size_t)(g0 + rr) * 16 + n;
            *(uint4*)&WhF[fi * 8] = *(uint4*)pk4;
        }
    }

    float a1v = a[hh * 64 + d];
    float a2v = a[hh * 64 + 32 + d];
    #pragma unroll
    for (int r = 0; r < 16; ++r) {
        float s1 = acc[r] * a1v;
        float s2 = acc[r] * a2v;
        #pragma unroll
        for (int off = 16; off >= 1; off >>= 1) {
            s1 += __shfl_xor(s1, off, 32);
            s2 += __shfl_xor(s2, off, 32);
        }
        if (d == 0) {
            int n = n0 + rq * 16 + r;
            src[(b * H_ + hh) * N_ + n] = s1 * LOG2E_;
            unsigned u = __builtin_bit_cast(unsigned, s2 * LOG2E_);
            u = (u + 0x7fffu + ((u >> 16) & 1u)) >> 16;
            dstb[(b * H_ + hh) * N_ + n] = (unsigned short)u;
        }
    }
}

// ------ main: R10 shell + coalesced fragment loads from WhF ------------------
__global__ __launch_bounds__(256, 4) void gat_main9(
    const int* __restrict__ adj, const unsigned short* __restrict__ WhF,
    const float* __restrict__ src, const unsigned short* __restrict__ dstb,
    float* __restrict__ out)
{
    __shared__ unsigned short dsts[H_ * N_];   // 16 KB
    __shared__ unsigned adjW[16][68];          // row stride 68: pad

    int bx = blockIdx.x;
    int b = bx >> 7;
    int i0 = (bx & 127) * 16;
    int tid = threadIdx.x;
    int wv = tid >> 6, l = tid & 63;

    #pragma unroll
    for (int it = 0; it < 4; ++it) {           // dst: 8192 ushorts = 1024 uint4
        int idx = it * 256 + tid;
        *(uint4*)&dsts[idx * 8] = *(const uint4*)&dstb[(size_t)b * H_ * N_ + idx * 8];
    }

    // adj staging: wave wv owns rows wv*4..+3; ballot packs 64 ints -> u64
    const int* adjBase = adj + ((size_t)(b * N_ + i0 + wv * 4)) * N_ + l;

    int vals[32];                              // in-flight group: 4 rows x 8 chunks
    #pragma unroll
    for (int rr = 0; rr < 4; ++rr)
        #pragma unroll
        for (int cc = 0; cc < 8; ++cc)
            vals[rr * 8 + cc] = adjBase[rr * N_ + cc * 64];

    int h = wv, g = l >> 4, m = l & 15;
    int g8 = g << 3;
    float src_r = src[(b * H_ + h) * N_ + i0 + m];
    // fragment-contiguous B: per (b,h): 64 chunks x 1024 elem; lane slice = l*8
    const unsigned short* WhB = WhF + ((size_t)(b * H_ + h) * 64) * 1024 + l * 8;
    const unsigned short* dstH = &dsts[h * N_];

    short8 ones;
    #pragma unroll
    for (int q = 0; q < 8; ++q) ones[q] = (short)0x3F80;   // bf16 1.0

    floatx4 acc0 = {0.f, 0.f, 0.f, 0.f};
    floatx4 acc1 = {0.f, 0.f, 0.f, 0.f};
    floatx4 acc2 = {0.f, 0.f, 0.f, 0.f};

    short8 bf0_c = *(const short8*)&WhB[0];    // chunk 0, half 0
    short8 bf1_c = *(const short8*)&WhB[512];  // chunk 0, half 1
    uint4 dv_c;                                // valid after first barrier

    for (int q = 0; q < 4; ++q) {
        // ---- ballot group q into LDS (loads already in flight)
        #pragma unroll
        for (int rr = 0; rr < 4; ++rr)
            #pragma unroll
            for (int cc = 0; cc < 8; ++cc) {
                unsigned long long mk = __ballot(vals[rr * 8 + cc] != 0);
                if (l == 0) {
                    int c = q * 8 + cc;
                    adjW[wv * 4 + rr][2 * c]     = (unsigned)mk;
                    adjW[wv * 4 + rr][2 * c + 1] = (unsigned)(mk >> 32);
                }
            }
        __syncthreads();                        // staging q visible to all waves
        if (q == 0) dv_c = *(const uint4*)&dstH[g8];

        // ---- issue group q+1 adj loads (hidden behind compute below)
        if (q < 3) {
            #pragma unroll
            for (int rr = 0; rr < 4; ++rr)
                #pragma unroll
                for (int cc = 0; cc < 8; ++cc)
                    vals[rr * 8 + cc] = adjBase[rr * N_ + (q + 1) * 512 + cc * 64];
        }

        // ---- compute 16 MFMA K-chunks of group q
        for (int jj = 0; jj < 16; ++jj) {
            int it = q * 16 + jj;
            int fn = (it + 1) * 1024;           // next chunk (it=63: harmless overread)
            short8 bf0_n = *(const short8*)&WhB[fn];
            short8 bf1_n = *(const short8*)&WhB[fn + 512];
            int j0n = ((it + 1) << 5) + g8;
            uint4  dv_n  = *(const uint4*)&dstH[(j0n < 2048) ? j0n : g8];

            unsigned sh = adjW[m][it] >> g8;    // broadcast read, this lane's 8 bits
            const unsigned* du = (const unsigned*)&dv_c;
            unsigned pk[4];
            #pragma unroll
            for (int c2 = 0; c2 < 4; ++c2) {
                float dlo = __builtin_bit_cast(float, du[c2] << 16);
                float dhi = __builtin_bit_cast(float, du[c2] & 0xffff0000u);
                float e0 = src_r + dlo;
                float e1 = src_r + dhi;
                e0 = fmaxf(e0, ALPHA_ * e0);    // lrelu (log2e>0 commutes)
                e1 = fmaxf(e1, ALPHA_ * e1);
                float m0 = (float)((sh >> (2 * c2)) & 1u);      // vcc-free mask
                float m1 = (float)((sh >> (2 * c2 + 1)) & 1u);
                float x0 = fexp2(e0) * m0;
                float x1 = fexp2(e1) * m1;
                pk[c2] = pktrunc(x0, x1);       // 1-op truncating bf16 pack
            }
            short8 af = __builtin_bit_cast(short8, *(uint4*)pk);
            acc0 = __builtin_amdgcn_mfma_f32_16x16x32_bf16(af, bf0_c, acc0, 0, 0, 0);
            acc1 = __builtin_amdgcn_mfma_f32_16x16x32_bf16(af, bf1_c, acc1, 0, 0, 0);
            acc2 = __builtin_amdgcn_mfma_f32_16x16x32_bf16(af, ones,  acc2, 0, 0, 0);
            bf0_c = bf0_n; bf1_c = bf1_n; dv_c = dv_n;
        }
    }

    // C/D: col = m, row = g*4 + r; acc2[r] = wsum for that row (all cols equal)
    #pragma unroll
    for (int r = 0; r < 4; ++r) {
        float inv = __builtin_amdgcn_rcpf(acc2[r]);
        size_t o = ((size_t)b * N_ + i0 + g * 4 + r) * HD_ + h * 32 + m;
        out[o]      = acc0[r] * inv;
        out[o + 16] = acc1[r] * inv;
    }
}

extern "C" void kernel_launch(void* const* d_in, const int* in_sizes, int n_in,
                              void* d_out, int out_size, void* d_ws, size_t ws_size,
                              hipStream_t stream) {
    const float* h   = (const float*)d_in[0];
    const int*   adj = (const int*)d_in[1];
    const float* W   = (const float*)d_in[2];
    const float* a   = (const float*)d_in[3];
    float* out = (float*)d_out;

    unsigned short* WhF  = (unsigned short*)d_ws;
    float*          src  = (float*)((char*)d_ws + 4u * 1024 * 1024);
    unsigned short* dstb = (unsigned short*)((char*)d_ws + 4u * 1024 * 1024 + 256u * 1024);

    gat_prep3<<<B_ * (N_ / 32), 256, 0, stream>>>(h, W, a, WhF, src, dstb);
    gat_main9<<<B_ * (N_ / 16), 256, 0, stream>>>(adj, WhF, src, dstb, out);
}

// Round 13
// 235.785 us; speedup vs baseline: 1.1715x; 1.0171x over previous
//
#include <hip/hip_runtime.h>
#include <hip/hip_bf16.h>

typedef short short8 __attribute__((ext_vector_type(8)));
typedef float floatx4 __attribute__((ext_vector_type(4)));

#define B_   8
#define N_   2048
#define FIN_ 64
#define H_   4
#define D_   32
#define HD_  128
#define JH_  1024
#define ALPHA_ 0.2f
#define LOG2E_ 1.4426950408889634f

// ws layout (bytes):
//   WhF  bf16 [B][H][64 chunk][2 dhalf][64 lane][8] @ 0      (4 MB)  frag-contiguous
//   src  fp32 [B][H][N] (x log2e)                   @ 4 MB   (256 KB)
//   dstb bf16 [B][H][N] (x log2e)                   @ 4.25MB (128 KB)
//   pO   fp32 [2][B][N][HD]                         @ 8 MB   (16 MB)
//   pW   fp32 [2][B][H][N]                          @ 24 MB  (512 KB)

__device__ __forceinline__ float fexp2(float x) {
#if __has_builtin(__builtin_amdgcn_exp2f)
    return __builtin_amdgcn_exp2f(x);
#else
    float r; asm("v_exp_f32 %0, %1" : "=v"(r) : "v"(x)); return r;
#endif
}

__device__ __forceinline__ unsigned pk2bf(float x, float y) {   // RNE pack (prep only)
    unsigned ux = __builtin_bit_cast(unsigned, x);
    ux = (ux + 0x7fffu + ((ux >> 16) & 1u)) >> 16;
    unsigned uy = __builtin_bit_cast(unsigned, y);
    uy = (uy + 0x7fffu + ((uy >> 16) & 1u)) >> 16;
    return ux | (uy << 16);
}

// truncating pack of two fp32 high halves -> one instr (v_perm_b32)
__device__ __forceinline__ unsigned pktrunc(float x, float y) {
    unsigned ux = __builtin_bit_cast(unsigned, x);
    unsigned uy = __builtin_bit_cast(unsigned, y);
#if __has_builtin(__builtin_amdgcn_perm)
    return __builtin_amdgcn_perm(uy, ux, 0x07060302u);  // {hi16(y), hi16(x)}
#else
    return (ux >> 16) | (uy & 0xffff0000u);
#endif
}

// ---- prep: Wh = h@W; WhF fragment-layout bf16, src/dst (x log2e) ------------
__global__ __launch_bounds__(256) void gat_prep3(
    const float* __restrict__ h, const float* __restrict__ W, const float* __restrict__ a,
    unsigned short* __restrict__ WhF, float* __restrict__ src, unsigned short* __restrict__ dstb)
{
    __shared__ float Ws[FIN_][HD_];
    __shared__ float hsT[FIN_][36];
    int bx = blockIdx.x;
    int b = bx >> 6;
    int n0 = (bx & 63) * 32;            // 32 graph nodes (j) per block
    int tid = threadIdx.x;

    #pragma unroll
    for (int it = 0; it < 8; ++it) {
        int idx = it * 256 + tid;
        int k = idx >> 5, c4 = (idx & 31) << 2;
        *(float4*)&Ws[k][c4] = *(const float4*)&W[k * HD_ + c4];
    }
    #pragma unroll
    for (int it = 0; it < 8; ++it) {
        int idx = it * 256 + tid;
        int r = idx >> 6, k = idx & 63;
        hsT[k][r] = h[((size_t)b * N_ + n0 + r) * FIN_ + k];
    }
    __syncthreads();

    int c = tid & 127;                  // output column = h*32+d
    int rq = tid >> 7;                  // 16-row half
    int hh = c >> 5, d = c & 31;
    float acc[16];
    #pragma unroll
    for (int r = 0; r < 16; ++r) acc[r] = 0.f;
    for (int k = 0; k < FIN_; ++k) {
        float wv = Ws[k][c];
        float4 h0 = *(const float4*)&hsT[k][rq * 16];
        float4 h1 = *(const float4*)&hsT[k][rq * 16 + 4];
        float4 h2 = *(const float4*)&hsT[k][rq * 16 + 8];
        float4 h3 = *(const float4*)&hsT[k][rq * 16 + 12];
        acc[0]  += h0.x * wv; acc[1]  += h0.y * wv; acc[2]  += h0.z * wv; acc[3]  += h0.w * wv;
        acc[4]  += h1.x * wv; acc[5]  += h1.y * wv; acc[6]  += h1.z * wv; acc[7]  += h1.w * wv;
        acc[8]  += h2.x * wv; acc[9]  += h2.y * wv; acc[10] += h2.z * wv; acc[11] += h2.w * wv;
        acc[12] += h3.x * wv; acc[13] += h3.y * wv; acc[14] += h3.z * wv; acc[15] += h3.w * wv;
    }

    // FragB write: Wh[j = n0+rq*16+r][col c] -> WhF[b][hh][it][dhalf][g*16+n][e]
    //   it = j>>5, g = (j>>3)&3, e = j&7, dhalf = d>>4, n = d&15
    {
        int half = d >> 4, n = d & 15;
        int j0 = n0 + rq * 16;
        int it0 = j0 >> 5;
        int g0 = (j0 >> 3) & 3;         // 0 or 2; spans g0, g0+1
        #pragma unroll
        for (int rr = 0; rr < 2; ++rr) {
            __attribute__((aligned(16))) unsigned pk4[4];
            #pragma unroll
            for (int q = 0; q < 4; ++q)
                pk4[q] = pk2bf(acc[rr * 8 + 2 * q], acc[rr * 8 + 2 * q + 1]);
            size_t fi = ((((size_t)b * H_ + hh) * 64 + it0) * 2 + half) * 64
                        + (size_t)(g0 + rr) * 16 + n;
            *(uint4*)&WhF[fi * 8] = *(uint4*)pk4;
        }
    }

    float a1v = a[hh * 64 + d];
    float a2v = a[hh * 64 + 32 + d];
    #pragma unroll
    for (int r = 0; r < 16; ++r) {
        float s1 = acc[r] * a1v;
        float s2 = acc[r] * a2v;
        #pragma unroll
        for (int off = 16; off >= 1; off >>= 1) {
            s1 += __shfl_xor(s1, off, 32);
            s2 += __shfl_xor(s2, off, 32);
        }
        if (d == 0) {
            int n = n0 + rq * 16 + r;
            src[(b * H_ + hh) * N_ + n] = s1 * LOG2E_;
            unsigned u = __builtin_bit_cast(unsigned, s2 * LOG2E_);
            u = (u + 0x7fffu + ((u >> 16) & 1u)) >> 16;
            dstb[(b * H_ + hh) * N_ + n] = (unsigned short)u;
        }
    }
}

// ------ main: j-split x2 (8 blk/CU @ 48 VGPR), coalesced WhF frags -----------
__global__ __launch_bounds__(256, 4) void gat_main10(
    const int* __restrict__ adj, const unsigned short* __restrict__ WhF,
    const float* __restrict__ src, const unsigned short* __restrict__ dstb,
    float* __restrict__ pO, float* __restrict__ pW)
{
    __shared__ unsigned short dsts[H_ * JH_];  // 8 KB (this j-half)
    __shared__ unsigned adjW[16][36];          // 32 words + pad

    int bx = blockIdx.x;
    int b    = bx >> 8;
    int rest = bx & 255;
    int half = rest & 1;
    int i0   = (rest >> 1) * 16;
    int jb   = half * JH_;
    int tid = threadIdx.x;
    int wv = tid >> 6, l = tid & 63;

    #pragma unroll
    for (int it = 0; it < 2; ++it) {           // dst half: 4096 ushorts = 512 uint4
        int idx = it * 256 + tid;
        int hh = idx >> 7, off = (idx & 127) * 8;
        *(uint4*)&dsts[hh * JH_ + off] =
            *(const uint4*)&dstb[(size_t)(b * H_ + hh) * N_ + jb + off];
    }

    // adj staging: wave wv owns rows wv*4..+3 of this j-half; ballot packs 64->u64
    const int* adjBase = adj + ((size_t)(b * N_ + i0 + wv * 4)) * N_ + jb + l;

    int vals[16];                              // in-flight group: 4 rows x 4 chunks
    #pragma unroll
    for (int rr = 0; rr < 4; ++rr)
        #pragma unroll
        for (int cc = 0; cc < 4; ++cc)
            vals[rr * 4 + cc] = adjBase[rr * N_ + cc * 64];

    int h = wv, g = l >> 4, m = l & 15;
    int g8 = g << 3;
    float src_r = src[(b * H_ + h) * N_ + i0 + m];
    // fragment-contiguous B: chunk c at offset c*1024; this half starts at chunk half*32
    const unsigned short* WhB =
        WhF + (((size_t)(b * H_ + h) * 64 + half * 32)) * 1024 + l * 8;
    const unsigned short* dstH = &dsts[h * JH_];

    short8 ones;
    #pragma unroll
    for (int q = 0; q < 8; ++q) ones[q] = (short)0x3F80;   // bf16 1.0

    floatx4 acc0 = {0.f, 0.f, 0.f, 0.f};
    floatx4 acc1 = {0.f, 0.f, 0.f, 0.f};
    floatx4 acc2 = {0.f, 0.f, 0.f, 0.f};

    short8 bf0_c = *(const short8*)&WhB[0];    // chunk 0, dhalf 0
    short8 bf1_c = *(const short8*)&WhB[512];  // chunk 0, dhalf 1
    uint4 dv_c;                                // valid after first barrier

    for (int q = 0; q < 4; ++q) {
        // ---- ballot group q into LDS (loads already in flight)
        #pragma unroll
        for (int rr = 0; rr < 4; ++rr)
            #pragma unroll
            for (int cc = 0; cc < 4; ++cc) {
                unsigned long long mk = __ballot(vals[rr * 4 + cc] != 0);
                if (l == 0) {
                    int c = q * 4 + cc;
                    adjW[wv * 4 + rr][2 * c]     = (unsigned)mk;
                    adjW[wv * 4 + rr][2 * c + 1] = (unsigned)(mk >> 32);
                }
            }
        __syncthreads();                        // staging q visible to all waves
        if (q == 0) dv_c = *(const uint4*)&dstH[g8];

        // ---- issue group q+1 adj loads (hidden behind compute below)
        if (q < 3) {
            #pragma unroll
            for (int rr = 0; rr < 4; ++rr)
                #pragma unroll
                for (int cc = 0; cc < 4; ++cc)
                    vals[rr * 4 + cc] = adjBase[rr * N_ + (q + 1) * 256 + cc * 64];
        }

        // ---- compute 8 MFMA K-chunks of group q (j in [q*256, q*256+256))
        for (int jj = 0; jj < 8; ++jj) {
            int it = q * 8 + jj;
            int fn = (it + 1) * 1024;           // next chunk (it=31: in-ws overread)
            short8 bf0_n = *(const short8*)&WhB[fn];
            short8 bf1_n = *(const short8*)&WhB[fn + 512];
            int j0n = ((it + 1) << 5) + g8;
            uint4  dv_n  = *(const uint4*)&dstH[(j0n < JH_) ? j0n : g8];

            unsigned sh = adjW[m][it] >> g8;    // broadcast read, this lane's 8 bits
            const unsigned* du = (const unsigned*)&dv_c;
            unsigned pk[4];
            #pragma unroll
            for (int c2 = 0; c2 < 4; ++c2) {
                float dlo = __builtin_bit_cast(float, du[c2] << 16);
                float dhi = __builtin_bit_cast(float, du[c2] & 0xffff0000u);
                float e0 = src_r + dlo;
                float e1 = src_r + dhi;
                e0 = fmaxf(e0, ALPHA_ * e0);    // lrelu (log2e>0 commutes)
                e1 = fmaxf(e1, ALPHA_ * e1);
                float m0 = (float)((sh >> (2 * c2)) & 1u);      // vcc-free mask
                float m1 = (float)((sh >> (2 * c2 + 1)) & 1u);
                float x0 = fexp2(e0) * m0;
                float x1 = fexp2(e1) * m1;
                pk[c2] = pktrunc(x0, x1);       // 1-op truncating bf16 pack
            }
            short8 af = __builtin_bit_cast(short8, *(uint4*)pk);
            acc0 = __builtin_amdgcn_mfma_f32_16x16x32_bf16(af, bf0_c, acc0, 0, 0, 0);
            acc1 = __builtin_amdgcn_mfma_f32_16x16x32_bf16(af, bf1_c, acc1, 0, 0, 0);
            acc2 = __builtin_amdgcn_mfma_f32_16x16x32_bf16(af, ones,  acc2, 0, 0, 0);
            bf0_c = bf0_n; bf1_c = bf1_n; dv_c = dv_n;
        }
    }

    // partial row-sums + partial PV (C/D: col=m, row=g*4+r)
    if (m == 0) {
        #pragma unroll
        for (int r = 0; r < 4; ++r)
            pW[(((size_t)half * B_ + b) * H_ + h) * N_ + i0 + g * 4 + r] = acc2[r];
    }
    #pragma unroll
    for (int r = 0; r < 4; ++r) {
        size_t o = ((size_t)(half * B_ + b) * N_ + i0 + g * 4 + r) * HD_ + h * 32 + m;
        pO[o]      = acc0[r];
        pO[o + 16] = acc1[r];
    }
}

// ---------------- finalize: sum halves, divide by wsum, write out ------------
__global__ __launch_bounds__(256) void gat_fin(
    const float* __restrict__ pO, const float* __restrict__ pW, float* __restrict__ out)
{
    int gid = blockIdx.x * 256 + threadIdx.x;    // float4 index, 524288 total
    int c4 = (gid & 31) << 2;
    int i  = (gid >> 5) & (N_ - 1);
    int b  = gid >> 16;
    int hh = c4 >> 5;
    float w0 = pW[((size_t)b * H_ + hh) * N_ + i];
    float w1 = pW[(((size_t)B_ + b) * H_ + hh) * N_ + i];
    float inv = 1.f / (w0 + w1);
    size_t o = ((size_t)b * N_ + i) * HD_ + c4;
    float4 v0 = *(const float4*)&pO[o];
    float4 v1 = *(const float4*)&pO[(size_t)B_ * N_ * HD_ + o];
    float4 r;
    r.x = (v0.x + v1.x) * inv;
    r.y = (v0.y + v1.y) * inv;
    r.z = (v0.z + v1.z) * inv;
    r.w = (v0.w + v1.w) * inv;
    *(float4*)&out[o] = r;
}

extern "C" void kernel_launch(void* const* d_in, const int* in_sizes, int n_in,
                              void* d_out, int out_size, void* d_ws, size_t ws_size,
                              hipStream_t stream) {
    const float* h   = (const float*)d_in[0];
    const int*   adj = (const int*)d_in[1];
    const float* W   = (const float*)d_in[2];
    const float* a   = (const float*)d_in[3];
    float* out = (float*)d_out;

    unsigned short* WhF  = (unsigned short*)d_ws;
    float*          src  = (float*)((char*)d_ws + 4u * 1024 * 1024);
    unsigned short* dstb = (unsigned short*)((char*)d_ws + 4u * 1024 * 1024 + 256u * 1024);
    float*          pO   = (float*)((char*)d_ws + 8u * 1024 * 1024);
    float*          pW   = (float*)((char*)d_ws + 24u * 1024 * 1024);

    gat_prep3<<<B_ * (N_ / 32), 256, 0, stream>>>(h, W, a, WhF, src, dstb);
    gat_main10<<<B_ * (N_ / 16) * 2, 256, 0, stream>>>(adj, WhF, src, dstb, pO, pW);
    gat_fin<<<(B_ * N_ * HD_ / 4) / 256, 256, 0, stream>>>(pO, pW, out);
}

// Round 15
// 230.263 us; speedup vs baseline: 1.1996x; 1.0240x over previous
//
#include <hip/hip_runtime.h>

typedef short short8 __attribute__((ext_vector_type(8)));
typedef _Float16 half8 __attribute__((ext_vector_type(8)));
typedef _Float16 half2v __attribute__((ext_vector_type(2)));
typedef float floatx4 __attribute__((ext_vector_type(4)));

extern "C" __device__ _Float16 __ocml_exp2_f16(_Float16);

#define B_   8
#define N_   2048
#define FIN_ 64
#define H_   4
#define D_   32
#define HD_  128
#define JH_  1024
#define ALPHA_ 0.2f
#define LOG2E_ 1.4426950408889634f

// ws layout (bytes):
//   WhF  f16 [B][H][64 chunk][2 dhalf][64 lane][8] @ 0      (4 MB)  frag-contiguous
//   src  fp32 [B][H][N] (x log2e)                  @ 4 MB   (256 KB)
//   dstb f16 [B][H][N] (x log2e)                   @ 4.25MB (128 KB)
//   pO   fp32 [2][B][N][HD]                        @ 8 MB   (16 MB)
//   pW   fp32 [2][B][H][N]                         @ 24 MB  (512 KB)

// ---- prep: Wh = h@W; WhF fragment-layout f16, src/dst (x log2e) -------------
__global__ __launch_bounds__(256) void gat_prep4(
    const float* __restrict__ h, const float* __restrict__ W, const float* __restrict__ a,
    unsigned short* __restrict__ WhF, float* __restrict__ src, unsigned short* __restrict__ dstb)
{
    __shared__ float Ws[FIN_][HD_];
    __shared__ float hsT[FIN_][36];
    int bx = blockIdx.x;
    int b = bx >> 6;
    int n0 = (bx & 63) * 32;            // 32 graph nodes (j) per block
    int tid = threadIdx.x;

    #pragma unroll
    for (int it = 0; it < 8; ++it) {
        int idx = it * 256 + tid;
        int k = idx >> 5, c4 = (idx & 31) << 2;
        *(float4*)&Ws[k][c4] = *(const float4*)&W[k * HD_ + c4];
    }
    #pragma unroll
    for (int it = 0; it < 8; ++it) {
        int idx = it * 256 + tid;
        int r = idx >> 6, k = idx & 63;
        hsT[k][r] = h[((size_t)b * N_ + n0 + r) * FIN_ + k];
    }
    __syncthreads();

    int c = tid & 127;                  // output column = h*32+d
    int rq = tid >> 7;                  // 16-row half
    int hh = c >> 5, d = c & 31;
    float acc[16];
    #pragma unroll
    for (int r = 0; r < 16; ++r) acc[r] = 0.f;
    for (int k = 0; k < FIN_; ++k) {
        float wv = Ws[k][c];
        float4 h0 = *(const float4*)&hsT[k][rq * 16];
        float4 h1 = *(const float4*)&hsT[k][rq * 16 + 4];
        float4 h2 = *(const float4*)&hsT[k][rq * 16 + 8];
        float4 h3 = *(const float4*)&hsT[k][rq * 16 + 12];
        acc[0]  += h0.x * wv; acc[1]  += h0.y * wv; acc[2]  += h0.z * wv; acc[3]  += h0.w * wv;
        acc[4]  += h1.x * wv; acc[5]  += h1.y * wv; acc[6]  += h1.z * wv; acc[7]  += h1.w * wv;
        acc[8]  += h2.x * wv; acc[9]  += h2.y * wv; acc[10] += h2.z * wv; acc[11] += h2.w * wv;
        acc[12] += h3.x * wv; acc[13] += h3.y * wv; acc[14] += h3.z * wv; acc[15] += h3.w * wv;
    }

    // FragB write (f16): Wh[j=n0+rq*16+r][col c] -> WhF[b][hh][it][dhalf][g*16+n][e]
    {
        int half = d >> 4, n = d & 15;
        int j0 = n0 + rq * 16;
        int it0 = j0 >> 5;
        int g0 = (j0 >> 3) & 3;         // 0 or 2; spans g0, g0+1
        #pragma unroll
        for (int rr = 0; rr < 2; ++rr) {
            __attribute__((aligned(16))) unsigned pk4[4];
            #pragma unroll
            for (int q = 0; q < 4; ++q)
                pk4[q] = __builtin_bit_cast(unsigned,
                    __builtin_amdgcn_cvt_pkrtz(acc[rr * 8 + 2 * q], acc[rr * 8 + 2 * q + 1]));
            size_t fi = ((((size_t)b * H_ + hh) * 64 + it0) * 2 + half) * 64
                        + (size_t)(g0 + rr) * 16 + n;
            *(uint4*)&WhF[fi * 8] = *(uint4*)pk4;
        }
    }

    float a1v = a[hh * 64 + d];
    float a2v = a[hh * 64 + 32 + d];
    #pragma unroll
    for (int r = 0; r < 16; ++r) {
        float s1 = acc[r] * a1v;
        float s2 = acc[r] * a2v;
        #pragma unroll
        for (int off = 16; off >= 1; off >>= 1) {
            s1 += __shfl_xor(s1, off, 32);
            s2 += __shfl_xor(s2, off, 32);
        }
        if (d == 0) {
            int n = n0 + rq * 16 + r;
            src[(b * H_ + hh) * N_ + n] = s1 * LOG2E_;
            _Float16 hv = (_Float16)(s2 * LOG2E_);
            dstb[(b * H_ + hh) * N_ + n] = __builtin_bit_cast(unsigned short, hv);
        }
    }
}

// ------ main: f16 packed-math weights (2/instr), f16 MFMA, j-split x2 --------
__global__ __launch_bounds__(256, 4) void gat_main11(
    const int* __restrict__ adj, const unsigned short* __restrict__ WhF,
    const float* __restrict__ src, const unsigned short* __restrict__ dstb,
    float* __restrict__ pO, float* __restrict__ pW)
{
    __shared__ unsigned short dsts[H_ * JH_];  // 8 KB (this j-half, f16)
    __shared__ unsigned adjW[16][36];          // 32 words + pad

    int bx = blockIdx.x;
    int b    = bx >> 8;
    int rest = bx & 255;
    int half = rest & 1;
    int i0   = (rest >> 1) * 16;
    int jb   = half * JH_;
    int tid = threadIdx.x;
    int wv = tid >> 6, l = tid & 63;

    #pragma unroll
    for (int it = 0; it < 2; ++it) {           // dst half: 4096 f16 = 512 uint4
        int idx = it * 256 + tid;
        int hh = idx >> 7, off = (idx & 127) * 8;
        *(uint4*)&dsts[hh * JH_ + off] =
            *(const uint4*)&dstb[(size_t)(b * H_ + hh) * N_ + jb + off];
    }

    // adj staging: wave wv owns rows wv*4..+3 of this j-half; ballot packs 64->u64
    const int* adjBase = adj + ((size_t)(b * N_ + i0 + wv * 4)) * N_ + jb + l;

    int vals[16];                              // in-flight group: 4 rows x 4 chunks
    #pragma unroll
    for (int rr = 0; rr < 4; ++rr)
        #pragma unroll
        for (int cc = 0; cc < 4; ++cc)
            vals[rr * 4 + cc] = adjBase[rr * N_ + cc * 64];

    int h = wv, g = l >> 4, m = l & 15;
    int g8 = g << 3;
    _Float16 sv = (_Float16)src[(b * H_ + h) * N_ + i0 + m];
    half2v s2; s2[0] = sv; s2[1] = sv;
    const _Float16 alf = (_Float16)0.2f;
    // fragment-contiguous B: chunk c at offset c*1024; this half starts at chunk half*32
    const unsigned short* WhB =
        WhF + (((size_t)(b * H_ + h) * 64 + half * 32)) * 1024 + l * 8;
    const unsigned short* dstH = &dsts[h * JH_];

    short8 onesS;
    #pragma unroll
    for (int q = 0; q < 8; ++q) onesS[q] = (short)0x3C00;  // f16 1.0
    half8 ones = __builtin_bit_cast(half8, onesS);

    floatx4 acc0 = {0.f, 0.f, 0.f, 0.f};
    floatx4 acc1 = {0.f, 0.f, 0.f, 0.f};
    floatx4 acc2 = {0.f, 0.f, 0.f, 0.f};

    short8 bf0_c = *(const short8*)&WhB[0];    // chunk 0, dhalf 0
    short8 bf1_c = *(const short8*)&WhB[512];  // chunk 0, dhalf 1
    uint4 dv_c;                                // valid after first barrier

    for (int q = 0; q < 4; ++q) {
        // ---- ballot group q into LDS (loads already in flight)
        #pragma unroll
        for (int rr = 0; rr < 4; ++rr)
            #pragma unroll
            for (int cc = 0; cc < 4; ++cc) {
                unsigned long long mk = __ballot(vals[rr * 4 + cc] != 0);
                if (l == 0) {
                    int c = q * 4 + cc;
                    adjW[wv * 4 + rr][2 * c]     = (unsigned)mk;
                    adjW[wv * 4 + rr][2 * c + 1] = (unsigned)(mk >> 32);
                }
            }
        __syncthreads();                        // staging q visible to all waves
        if (q == 0) dv_c = *(const uint4*)&dstH[g8];

        // ---- issue group q+1 adj loads (hidden behind compute below)
        if (q < 3) {
            #pragma unroll
            for (int rr = 0; rr < 4; ++rr)
                #pragma unroll
                for (int cc = 0; cc < 4; ++cc)
                    vals[rr * 4 + cc] = adjBase[rr * N_ + (q + 1) * 256 + cc * 64];
        }

        // ---- compute 8 MFMA K-chunks of group q (j in [q*256, q*256+256))
        for (int jj = 0; jj < 8; ++jj) {
            int it = q * 8 + jj;
            int fn = (it + 1) * 1024;           // next chunk (it=31: in-ws overread)
            short8 bf0_n = *(const short8*)&WhB[fn];
            short8 bf1_n = *(const short8*)&WhB[fn + 512];
            int j0n = ((it + 1) << 5) + g8;
            uint4  dv_n  = *(const uint4*)&dstH[(j0n < JH_) ? j0n : g8];

            unsigned sh = adjW[m][it] >> g8;    // broadcast read, this lane's 8 bits
            const unsigned* du = (const unsigned*)&dv_c;
            __attribute__((aligned(16))) unsigned pk[4];
            #pragma unroll
            for (int c2 = 0; c2 < 4; ++c2) {
                half2v d2 = __builtin_bit_cast(half2v, du[c2]);
                half2v e2 = s2 + d2;                            // v_pk_add_f16
                half2v t2 = e2 * alf;                           // v_pk_mul_f16
                e2 = __builtin_elementwise_max(e2, t2);         // v_pk_max_f16 (lrelu)
                half2v x2;
                x2[0] = __ocml_exp2_f16(e2[0]);                 // v_exp_f16 x2
                x2[1] = __ocml_exp2_f16(e2[1]);
                unsigned mk = ((((sh >> (2 * c2 + 1)) & 1u) << 16)
                               | ((sh >> (2 * c2)) & 1u)) * 0x3C00u;  // {0,1} f16 pair
                x2 = x2 * __builtin_bit_cast(half2v, mk);       // v_pk_mul_f16 mask
                pk[c2] = __builtin_bit_cast(unsigned, x2);      // IS the A-frag pair
            }
            half8 af = __builtin_bit_cast(half8, *(uint4*)pk);
            acc0 = __builtin_amdgcn_mfma_f32_16x16x32_f16(
                       af, __builtin_bit_cast(half8, bf0_c), acc0, 0, 0, 0);
            acc1 = __builtin_amdgcn_mfma_f32_16x16x32_f16(
                       af, __builtin_bit_cast(half8, bf1_c), acc1, 0, 0, 0);
            acc2 = __builtin_amdgcn_mfma_f32_16x16x32_f16(af, ones, acc2, 0, 0, 0);
            bf0_c = bf0_n; bf1_c = bf1_n; dv_c = dv_n;
        }
    }

    // partial row-sums + partial PV (C/D: col=m, row=g*4+r)
    if (m == 0) {
        #pragma unroll
        for (int r = 0; r < 4; ++r)
            pW[(((size_t)half * B_ + b) * H_ + h) * N_ + i0 + g * 4 + r] = acc2[r];
    }
    #pragma unroll
    for (int r = 0; r < 4; ++r) {
        size_t o = ((size_t)(half * B_ + b) * N_ + i0 + g * 4 + r) * HD_ + h * 32 + m;
        pO[o]      = acc0[r];
        pO[o + 16] = acc1[r];
    }
}

// ---------------- finalize: sum halves, divide by wsum, write out ------------
__global__ __launch_bounds__(256) void gat_fin(
    const float* __restrict__ pO, const float* __restrict__ pW, float* __restrict__ out)
{
    int gid = blockIdx.x * 256 + threadIdx.x;    // float4 index, 524288 total
    int c4 = (gid & 31) << 2;
    int i  = (gid >> 5) & (N_ - 1);
    int b  = gid >> 16;
    int hh = c4 >> 5;
    float w0 = pW[((size_t)b * H_ + hh) * N_ + i];
    float w1 = pW[(((size_t)B_ + b) * H_ + hh) * N_ + i];
    float inv = 1.f / (w0 + w1);
    size_t o = ((size_t)b * N_ + i) * HD_ + c4;
    float4 v0 = *(const float4*)&pO[o];
    float4 v1 = *(const float4*)&pO[(size_t)B_ * N_ * HD_ + o];
    float4 r;
    r.x = (v0.x + v1.x) * inv;
    r.y = (v0.y + v1.y) * inv;
    r.z = (v0.z + v1.z) * inv;
    r.w = (v0.w + v1.w) * inv;
    *(float4*)&out[o] = r;
}

extern "C" void kernel_launch(void* const* d_in, const int* in_sizes, int n_in,
                              void* d_out, int out_size, void* d_ws, size_t ws_size,
                              hipStream_t stream) {
    const float* h   = (const float*)d_in[0];
    const int*   adj = (const int*)d_in[1];
    const float* W   = (const float*)d_in[2];
    const float* a   = (const float*)d_in[3];
    float* out = (float*)d_out;

    unsigned short* WhF  = (unsigned short*)d_ws;
    float*          src  = (float*)((char*)d_ws + 4u * 1024 * 1024);
    unsigned short* dstb = (unsigned short*)((char*)d_ws + 4u * 1024 * 1024 + 256u * 1024);
    float*          pO   = (float*)((char*)d_ws + 8u * 1024 * 1024);
    float*          pW   = (float*)((char*)d_ws + 24u * 1024 * 1024);

    gat_prep4<<<B_ * (N_ / 32), 256, 0, stream>>>(h, W, a, WhF, src, dstb);
    gat_main11<<<B_ * (N_ / 16) * 2, 256, 0, stream>>>(adj, WhF, src, dstb, pO, pW);
    gat_fin<<<(B_ * N_ * HD_ / 4) / 256, 256, 0, stream>>>(pO, pW, out);
}